// Round 4
// baseline (14328.688 us; speedup 1.0000x reference)
//
#include <hip/hip_runtime.h>
#include <hip/hip_bf16.h>

#define BATCH 64
#define HID 512
#define EMB 256
#define VOCAB 32000
#define G4 2048   // 4*HID

// ---------------- zero init ----------------
__global__ __launch_bounds__(256) void zero_kernel(float* p, int n){
    int i = blockIdx.x*256 + threadIdx.x;
    if (i < n) p[i] = 0.f;
}

// ---------------- embedding gather ----------------
__global__ __launch_bounds__(256) void embed_kernel(const int* __restrict__ tok,
                                                    const float* __restrict__ emb,
                                                    float* __restrict__ out, int T){
    int i = blockIdx.x*256 + threadIdx.x;
    int n = T*BATCH*(EMB/4);
    if (i >= n) return;
    int e4 = i % (EMB/4);
    int tb = i / (EMB/4);
    int id = tok[tb];
    reinterpret_cast<float4*>(out)[(size_t)tb*(EMB/4) + e4] =
        reinterpret_cast<const float4*>(emb + (size_t)id*EMB)[e4];
}

// ---------------- generic fp32 GEMM:  C[n,m] = A[n,:K] . B[m,:K] + bias[m] ----------------
__global__ __launch_bounds__(256) void gemm_nt(const float* __restrict__ A,
                                               const float* __restrict__ B,
                                               const float* __restrict__ bias,
                                               float* __restrict__ C,
                                               int N, int M, int K){
    __shared__ float As[16][65];
    __shared__ float Bs[16][65];
    int m0 = blockIdx.x*64, n0 = blockIdx.y*64;
    int tid = threadIdx.x;
    int tx = tid & 15, ty = tid >> 4;
    float acc[4][4] = {};
    for (int k0 = 0; k0 < K; k0 += 16){
        for (int i = tid; i < 64*16; i += 256){
            int r = i >> 4, k = i & 15;
            As[k][r] = A[(size_t)(n0+r)*K + k0 + k];
            Bs[k][r] = B[(size_t)(m0+r)*K + k0 + k];
        }
        __syncthreads();
        #pragma unroll
        for (int k = 0; k < 16; k++){
            float a[4], b[4];
            #pragma unroll
            for (int i = 0; i < 4; i++) a[i] = As[k][ty*4+i];
            #pragma unroll
            for (int j = 0; j < 4; j++) b[j] = Bs[k][tx*4+j];
            #pragma unroll
            for (int i = 0; i < 4; i++)
                #pragma unroll
                for (int j = 0; j < 4; j++)
                    acc[i][j] += a[i]*b[j];
        }
        __syncthreads();
    }
    #pragma unroll
    for (int i = 0; i < 4; i++){
        int n = n0 + ty*4 + i;
        #pragma unroll
        for (int j = 0; j < 4; j++){
            int m = m0 + tx*4 + j;
            C[(size_t)n*M + m] = acc[i][j] + bias[m];
        }
    }
}

// ---------------- persistent LSTM layer ----------------
// Grid: exactly 256 blocks x 256 threads. Block bx: hc = bx&31 (16 hid), bc = bx>>5 (8 batch).
// Whh slice (64 rows x 512) register-resident: thread (r=tid&63, kc=tid>>6) holds
// row gr = (r>>4)*512 + hc*16 + (r&15), k-range [kc*128, kc*128+128) -> 32 float4 VGPRs.
// h(t-1) staged in LDS per step (16KB, broadcast reads). ys[t] doubles as h history ->
// no aliasing; one device-scope barrier per step (release fence + atomic ctr + acquire).
// LDS 24KB, ~200 VGPR -> all 256 blocks resident under any placement (no deadlock);
// spin bounded so a sync bug terminates (wrong) instead of hanging.
__global__ __launch_bounds__(256, 1) void lstm_layer_k(
    const float* __restrict__ Xp,    // [T*64, 2048] precomputed x@Wih^T + b
    const float* __restrict__ Whh,   // [2048, 512]
    const float* __restrict__ hinit, // [64, 512]
    const float* __restrict__ cinit, // [64, 512]
    float* __restrict__ ys,          // [T*64, 512] (h history + layer output)
    float* __restrict__ cfin,        // [64, 512]
    int T,
    unsigned* __restrict__ ctr)      // zeroed before launch
{
    __shared__ float hs[8*HID];      // 16 KB: block's 8 batch rows of h(t-1)
    __shared__ float red[4*64*8];    // 8 KB: k-partial / gate exchange

    const int bx  = blockIdx.x;
    const int hc  = bx & 31, bc = bx >> 5;
    const int hid0 = hc*16;
    const int tid = threadIdx.x;
    const int r   = tid & 63, kc = tid >> 6;   // kc uniform per wave
    const int g   = r >> 4, hl = r & 15;
    const int gr  = g*HID + hid0 + hl;         // Whh row

    // ---- weights -> registers (once per layer) ----
    float4 w[32];
    {
        const float4* wp = reinterpret_cast<const float4*>(Whh + (size_t)gr*HID) + kc*32;
        #pragma unroll
        for (int j = 0; j < 32; j++) w[j] = wp[j];
    }

    // ---- c state in registers of update threads (tid < 128) ----
    const int ub = tid >> 4;        // 0..7 batch (valid for tid<128)
    const int uh = tid & 15;        // 0..15 hid
    float creg = 0.f;
    if (tid < 128) creg = cinit[(size_t)(bc*8 + ub)*HID + hid0 + uh];

    const size_t hbase = (size_t)bc*8*HID;   // block's batch rows within a [64,512] plane

    for (int t = 0; t < T; t++){
        // ---- stage h(t-1) into LDS (coalesced, 4 float4/thread) ----
        const float4* hsrc4 = reinterpret_cast<const float4*>(
            (t == 0) ? (hinit + hbase) : (ys + (size_t)(t-1)*BATCH*HID + hbase));
        float4* hs4w = reinterpret_cast<float4*>(hs);
        #pragma unroll
        for (int j = 0; j < 4; j++) hs4w[tid + j*256] = hsrc4[tid + j*256];
        __syncthreads();

        // ---- partial dots: this thread's row x 8 batch over its 128-k range ----
        float4 a4[8];
        #pragma unroll
        for (int b = 0; b < 8; b++) a4[b] = float4{0.f,0.f,0.f,0.f};
        const float4* h4 = reinterpret_cast<const float4*>(hs) + kc*32;
        #pragma unroll
        for (int j = 0; j < 32; j++){
            float4 a = w[j];
            #pragma unroll
            for (int b = 0; b < 8; b++){
                float4 hv = h4[b*128 + j];   // wave-uniform addr -> broadcast
                a4[b].x += a.x*hv.x; a4[b].y += a.y*hv.y;
                a4[b].z += a.z*hv.z; a4[b].w += a.w*hv.w;
            }
        }
        #pragma unroll
        for (int b = 0; b < 8; b++)
            red[(kc*64 + r)*8 + b] = a4[b].x + a4[b].y + a4[b].z + a4[b].w;
        __syncthreads();

        // ---- k-reduce (kc slices) into red[0] region ----
        if (tid < 64){
            #pragma unroll
            for (int b = 0; b < 8; b++)
                red[tid*8 + b] = red[tid*8 + b] + red[(64+tid)*8 + b]
                               + red[(128+tid)*8 + b] + red[(192+tid)*8 + b];
        }
        __syncthreads();

        // ---- gates + state update (threads 0..127 own one (hid,b)) ----
        if (tid < 128){
            float gd0 = red[(0*16 + uh)*8 + ub];
            float gd1 = red[(1*16 + uh)*8 + ub];
            float gd2 = red[(2*16 + uh)*8 + ub];
            float gd3 = red[(3*16 + uh)*8 + ub];
            const float* xpr = Xp + (size_t)t*BATCH*G4 + (size_t)(bc*8 + ub)*G4 + hid0 + uh;
            float gi = gd0 + xpr[0];
            float gf = gd1 + xpr[512];
            float gg = gd2 + xpr[1024];
            float go = gd3 + xpr[1536];
            float si = 1.f/(1.f + expf(-gi));
            float sf = 1.f/(1.f + expf(-gf));
            float so = 1.f/(1.f + expf(-go));
            float tg = tanhf(gg);
            float c = sf*creg + si*tg;
            creg = c;
            ys[(size_t)t*BATCH*HID + (size_t)(bc*8 + ub)*HID + hid0 + uh] = so * tanhf(c);
        }

        // ---- device-wide barrier (skip after last step) ----
        if (t < T-1){
            __threadfence();          // per-wave release of h stores
            __syncthreads();          // all waves fenced before the arrive
            if (tid == 0){
                __hip_atomic_fetch_add(ctr, 1u, __ATOMIC_RELEASE,
                                       __HIP_MEMORY_SCOPE_AGENT);
                unsigned target = (unsigned)(t+1) * 256u;
                unsigned spins = 0;
                while (__hip_atomic_load(ctr, __ATOMIC_ACQUIRE,
                                         __HIP_MEMORY_SCOPE_AGENT) < target
                       && ++spins < (1u<<20)) {}
            }
            __syncthreads();
            __threadfence();          // acquire side before next hs load
        }
    }

    if (tid < 128)
        cfin[(size_t)(bc*8 + ub)*HID + hid0 + uh] = creg;
}

extern "C" void kernel_launch(void* const* d_in, const int* in_sizes, int n_in,
                              void* d_out, int out_size, void* d_ws, size_t ws_size,
                              hipStream_t stream) {
    const int*   src      = (const int*)  d_in[0];
    const int*   trg      = (const int*)  d_in[1];
    const float* enc_emb  = (const float*)d_in[2];
    const float* enc_Wih0 = (const float*)d_in[3];
    const float* enc_Whh0 = (const float*)d_in[4];
    const float* enc_b0   = (const float*)d_in[5];
    const float* enc_Wih1 = (const float*)d_in[6];
    const float* enc_Whh1 = (const float*)d_in[7];
    const float* enc_b1   = (const float*)d_in[8];
    const float* dec_emb  = (const float*)d_in[9];
    const float* dec_Wih0 = (const float*)d_in[10];
    const float* dec_Whh0 = (const float*)d_in[11];
    const float* dec_b0   = (const float*)d_in[12];
    const float* dec_Wih1 = (const float*)d_in[13];
    const float* dec_Whh1 = (const float*)d_in[14];
    const float* dec_b1   = (const float*)d_in[15];
    const float* out_W    = (const float*)d_in[16];
    const float* out_b    = (const float*)d_in[17];

    // Big transient scratch in d_out (fp32, 100.35M elems); all dead before final GEMM.
    float* ob = (float*)d_out;
    float* Xp   = ob;                         // [3200,2048]
    float* xe   = ob + (size_t)6553600;       // [3200,256]
    float* xd   = ob + (size_t)7372800;       // [3136,256]
    float* eys0 = ob + (size_t)8175616;       // [50*64,512]
    float* eys1 = ob + (size_t)9814016;       // [50*64,512]
    float* dys0 = ob + (size_t)11452416;      // [49*64,512]

    // d_ws: survivors + states + barrier counters.
    float* ws = (float*)d_ws;
    float* dys1 = ws;                              // [49*64,512] = 1,605,632
    float* c0   = ws + (size_t)1605632;            // [64,512]
    float* c1   = ws + (size_t)1638400;            // [64,512]
    float* hz   = ws + (size_t)1671168;            // [64,512] zeros (h AND c init)
    unsigned* ctrs = (unsigned*)(ws + (size_t)1703936);  // 4 counters, 16-float spaced

    // zero c0,c1,hz + counters (contiguous: 3*64*512 + 64 floats)
    {
        int n = 3*BATCH*HID + 64;
        zero_kernel<<<(n+255)/256, 256, 0, stream>>>(c0, n);
    }

    // embeddings
    embed_kernel<<<(50*BATCH*(EMB/4)+255)/256, 256, 0, stream>>>(src, enc_emb, xe, 50);
    embed_kernel<<<(49*BATCH*(EMB/4)+255)/256, 256, 0, stream>>>(trg, dec_emb, xd, 49);

    // ---- encoder layer 0 ----
    gemm_nt<<<dim3(G4/64, 3200/64), 256, 0, stream>>>(xe, enc_Wih0, enc_b0, Xp, 3200, G4, EMB);
    lstm_layer_k<<<256, 256, 0, stream>>>(Xp, enc_Whh0, hz, hz, eys0, c0, 50, ctrs + 0);

    // ---- encoder layer 1 ----
    gemm_nt<<<dim3(G4/64, 3200/64), 256, 0, stream>>>(eys0, enc_Wih1, enc_b1, Xp, 3200, G4, HID);
    lstm_layer_k<<<256, 256, 0, stream>>>(Xp, enc_Whh1, hz, hz, eys1, c1, 50, ctrs + 16);

    // ---- decoder layer 0 (h/c continue from encoder layer 0 finals) ----
    gemm_nt<<<dim3(G4/64, 3136/64), 256, 0, stream>>>(xd, dec_Wih0, dec_b0, Xp, 3136, G4, EMB);
    lstm_layer_k<<<256, 256, 0, stream>>>(Xp, dec_Whh0, eys0 + (size_t)49*BATCH*HID, c0,
                                          dys0, c0, 49, ctrs + 32);

    // ---- decoder layer 1 (h/c continue from encoder layer 1 finals) ----
    gemm_nt<<<dim3(G4/64, 3136/64), 256, 0, stream>>>(dys0, dec_Wih1, dec_b1, Xp, 3136, G4, HID);
    lstm_layer_k<<<256, 256, 0, stream>>>(Xp, dec_Whh1, eys1 + (size_t)49*BATCH*HID, c1,
                                          dys1, c1, 49, ctrs + 48);

    // ---- final projection -> fp32 d_out [3136, 32000] ----
    gemm_nt<<<dim3(VOCAB/64, 3136/64), 256, 0, stream>>>(dys1, out_W, out_b, (float*)d_out,
                                                         3136, VOCAB, HID);
}

// Round 5
// 10431.998 us; speedup vs baseline: 1.3735x; 1.3735x over previous
//
#include <hip/hip_runtime.h>
#include <hip/hip_bf16.h>

#define BATCH 64
#define HID 512
#define EMB 256
#define VOCAB 32000
#define G4 2048   // 4*HID

typedef __attribute__((ext_vector_type(8))) short short8;
typedef __attribute__((ext_vector_type(4))) float f32x4;

// ---------------- zero init ----------------
__global__ __launch_bounds__(256) void zero_kernel(float* p, int n){
    int i = blockIdx.x*256 + threadIdx.x;
    if (i < n) p[i] = 0.f;
}

// ---------------- embedding gather ----------------
__global__ __launch_bounds__(256) void embed_kernel(const int* __restrict__ tok,
                                                    const float* __restrict__ emb,
                                                    float* __restrict__ out, int T){
    int i = blockIdx.x*256 + threadIdx.x;
    int n = T*BATCH*(EMB/4);
    if (i >= n) return;
    int e4 = i % (EMB/4);
    int tb = i / (EMB/4);
    int id = tok[tb];
    reinterpret_cast<float4*>(out)[(size_t)tb*(EMB/4) + e4] =
        reinterpret_cast<const float4*>(emb + (size_t)id*EMB)[e4];
}

// round-to-nearest-even fp32 -> bf16 bits
__device__ __forceinline__ unsigned short bf16_rne(float x){
    unsigned b = __float_as_uint(x);
    return (unsigned short)((b + 0x7fffu + ((b >> 16) & 1u)) >> 16);
}

// ---------------- MFMA split-bf16 GEMM: C[n,m] = A[n,:K].B[m,:K] + bias[m] ----------------
// fp32 in/out; internally A,B split to bf16 hi/lo; C = AhBh + AhBl + AlBh (fp32 MFMA acc).
// Dropped Al*Bl term ~2^-18 relative. Tile 128x128, 4 waves of 64x64, mfma 16x16x32.
// KDIM mult of 32; NDIM mult of 128; M arbitrary (row-guarded).
template<int KDIM, int NDIM>
__global__ __launch_bounds__(256) void gemm_mfma_split(
    const float* __restrict__ A, const float* __restrict__ B,
    const float* __restrict__ bias, float* __restrict__ C, int M)
{
    constexpr int LS = 40;   // LDS row stride in bf16 elems (32 data + 8 pad -> 2-way banks)
    __shared__ unsigned short Ah[128*LS], Al[128*LS], Bh[128*LS], Bl[128*LS];
    const int n0 = blockIdx.x*128, m0 = blockIdx.y*128;
    const int tid  = threadIdx.x;
    const int lane = tid & 63, wid = tid >> 6;
    const int wm = wid >> 1, wn = wid & 1;        // wave -> 64x64 quadrant
    const int srow = tid >> 1, sk = (tid & 1)*16; // staging: 2 thr/row, 16 k each
    f32x4 acc[4][4] = {};

    for (int k0 = 0; k0 < KDIM; k0 += 32){
        __syncthreads();   // protect LDS from previous iteration's readers
        // ---- stage A tile (row-guarded) ----
        {
            int ar = m0 + srow;
            float xv[16];
            if (ar < M){
                const float4* ap = reinterpret_cast<const float4*>(A + (size_t)ar*KDIM + k0 + sk);
                #pragma unroll
                for (int q = 0; q < 4; q++){
                    float4 v = ap[q];
                    xv[q*4+0]=v.x; xv[q*4+1]=v.y; xv[q*4+2]=v.z; xv[q*4+3]=v.w;
                }
            } else {
                #pragma unroll
                for (int q = 0; q < 16; q++) xv[q] = 0.f;
            }
            #pragma unroll
            for (int q = 0; q < 16; q++){
                unsigned short h = bf16_rne(xv[q]);
                float hf = __uint_as_float((unsigned)h << 16);
                Ah[srow*LS + sk + q] = h;
                Al[srow*LS + sk + q] = bf16_rne(xv[q] - hf);
            }
        }
        // ---- stage B tile (NDIM multiple of 128 -> no guard) ----
        {
            int br = n0 + srow;
            const float4* bp = reinterpret_cast<const float4*>(B + (size_t)br*KDIM + k0 + sk);
            #pragma unroll
            for (int q = 0; q < 4; q++){
                float4 v = bp[q];
                float xs[4] = {v.x, v.y, v.z, v.w};
                #pragma unroll
                for (int j = 0; j < 4; j++){
                    unsigned short h = bf16_rne(xs[j]);
                    float hf = __uint_as_float((unsigned)h << 16);
                    Bh[srow*LS + sk + q*4 + j] = h;
                    Bl[srow*LS + sk + q*4 + j] = bf16_rne(xs[j] - hf);
                }
            }
        }
        __syncthreads();
        // ---- fragments + MFMA ----
        const int fr = lane & 15, fk = (lane >> 4)*8;
        short8 a_h[4], a_l[4], b_h[4], b_l[4];
        #pragma unroll
        for (int mi = 0; mi < 4; mi++){
            int row = wm*64 + mi*16 + fr;
            a_h[mi] = *reinterpret_cast<const short8*>(&Ah[row*LS + fk]);
            a_l[mi] = *reinterpret_cast<const short8*>(&Al[row*LS + fk]);
        }
        #pragma unroll
        for (int nj = 0; nj < 4; nj++){
            int rowb = wn*64 + nj*16 + fr;
            b_h[nj] = *reinterpret_cast<const short8*>(&Bh[rowb*LS + fk]);
            b_l[nj] = *reinterpret_cast<const short8*>(&Bl[rowb*LS + fk]);
        }
        #pragma unroll
        for (int mi = 0; mi < 4; mi++)
            #pragma unroll
            for (int nj = 0; nj < 4; nj++){
                acc[mi][nj] = __builtin_amdgcn_mfma_f32_16x16x32_bf16(a_h[mi], b_h[nj], acc[mi][nj], 0,0,0);
                acc[mi][nj] = __builtin_amdgcn_mfma_f32_16x16x32_bf16(a_h[mi], b_l[nj], acc[mi][nj], 0,0,0);
                acc[mi][nj] = __builtin_amdgcn_mfma_f32_16x16x32_bf16(a_l[mi], b_h[nj], acc[mi][nj], 0,0,0);
            }
    }
    // ---- epilogue: C/D layout col=lane&15, row=(lane>>4)*4+reg ----
    const int fr = lane & 15, fq = lane >> 4;
    #pragma unroll
    for (int nj = 0; nj < 4; nj++){
        int col = n0 + wn*64 + nj*16 + fr;
        float bv = bias[col];
        #pragma unroll
        for (int mi = 0; mi < 4; mi++){
            int rbase = m0 + wm*64 + mi*16 + fq*4;
            #pragma unroll
            for (int j = 0; j < 4; j++){
                int row = rbase + j;
                if (row < M)
                    __builtin_nontemporal_store(acc[mi][nj][j] + bv, &C[(size_t)row*NDIM + col]);
            }
        }
    }
}

// ---------------- persistent LSTM layer ----------------
// 256 blocks x 256 threads. Block (hc=bx&31, bc=bx>>5): 16 hid x 8 batch outputs.
// Whh slice register-resident. Cross-block dependency is only WITHIN a bc group
// (32 blocks) -> per-group barrier: one RELAXED-spin counter (no per-iteration
// acquire -> no L2-invalidate storm), single release/acquire __threadfence pair.
__global__ __launch_bounds__(256, 1) void lstm_layer_k(
    const float* __restrict__ Xp,    // [T*64, 2048]
    const float* __restrict__ Whh,   // [2048, 512]
    const float* __restrict__ hinit, // [64, 512]
    const float* __restrict__ cinit, // [64, 512]
    float* __restrict__ ys,          // [T*64, 512]
    float* __restrict__ cfin,        // [64, 512]
    int T,
    unsigned* __restrict__ ctrbase)  // 8 groups x 16 uints, zeroed
{
    __shared__ float hs[8*HID];      // 16 KB
    __shared__ float red[4*64*8];    // 8 KB

    const int bx  = blockIdx.x;
    const int hc  = bx & 31, bc = bx >> 5;
    const int hid0 = hc*16;
    const int tid = threadIdx.x;
    const int r   = tid & 63, kc = tid >> 6;
    const int g   = r >> 4, hl = r & 15;
    const int gr  = g*HID + hid0 + hl;
    unsigned* ctr = ctrbase + bc*16;     // per-bc-group counter (64B spaced)

    float4 w[32];
    {
        const float4* wp = reinterpret_cast<const float4*>(Whh + (size_t)gr*HID) + kc*32;
        #pragma unroll
        for (int j = 0; j < 32; j++) w[j] = wp[j];
    }

    const int ub = tid >> 4;        // batch (tid<128)
    const int uh = tid & 15;        // hid
    float creg = 0.f;
    if (tid < 128) creg = cinit[(size_t)(bc*8 + ub)*HID + hid0 + uh];

    const size_t hbase = (size_t)bc*8*HID;

    for (int t = 0; t < T; t++){
        // stage h(t-1) into LDS
        const float4* hsrc4 = reinterpret_cast<const float4*>(
            (t == 0) ? (hinit + hbase) : (ys + (size_t)(t-1)*BATCH*HID + hbase));
        float4* hs4w = reinterpret_cast<float4*>(hs);
        #pragma unroll
        for (int j = 0; j < 4; j++) hs4w[tid + j*256] = hsrc4[tid + j*256];
        __syncthreads();

        // partial dots
        float4 a4[8];
        #pragma unroll
        for (int b = 0; b < 8; b++) a4[b] = float4{0.f,0.f,0.f,0.f};
        const float4* h4 = reinterpret_cast<const float4*>(hs) + kc*32;
        #pragma unroll
        for (int j = 0; j < 32; j++){
            float4 a = w[j];
            #pragma unroll
            for (int b = 0; b < 8; b++){
                float4 hv = h4[b*128 + j];
                a4[b].x += a.x*hv.x; a4[b].y += a.y*hv.y;
                a4[b].z += a.z*hv.z; a4[b].w += a.w*hv.w;
            }
        }
        #pragma unroll
        for (int b = 0; b < 8; b++)
            red[(kc*64 + r)*8 + b] = a4[b].x + a4[b].y + a4[b].z + a4[b].w;
        __syncthreads();

        if (tid < 64){
            #pragma unroll
            for (int b = 0; b < 8; b++)
                red[tid*8 + b] = red[tid*8 + b] + red[(64+tid)*8 + b]
                               + red[(128+tid)*8 + b] + red[(192+tid)*8 + b];
        }
        __syncthreads();

        if (tid < 128){
            float gd0 = red[(0*16 + uh)*8 + ub];
            float gd1 = red[(1*16 + uh)*8 + ub];
            float gd2 = red[(2*16 + uh)*8 + ub];
            float gd3 = red[(3*16 + uh)*8 + ub];
            const float* xpr = Xp + (size_t)t*BATCH*G4 + (size_t)(bc*8 + ub)*G4 + hid0 + uh;
            float gi = gd0 + xpr[0];
            float gf = gd1 + xpr[512];
            float gg = gd2 + xpr[1024];
            float go = gd3 + xpr[1536];
            float si = 1.f/(1.f + expf(-gi));
            float sf = 1.f/(1.f + expf(-gf));
            float so = 1.f/(1.f + expf(-go));
            float tg = tanhf(gg);
            float c = sf*creg + si*tg;
            creg = c;
            ys[(size_t)t*BATCH*HID + (size_t)(bc*8 + ub)*HID + hid0 + uh] = so * tanhf(c);
        }

        // per-bc-group barrier (32 blocks), relaxed spin + single fence pair
        if (t < T-1){
            __threadfence();          // release: push h stores toward coherent point
            __syncthreads();
            if (tid == 0){
                __hip_atomic_fetch_add(ctr, 1u, __ATOMIC_RELAXED, __HIP_MEMORY_SCOPE_AGENT);
                unsigned target = (unsigned)(t+1) * 32u;
                unsigned spins = 0;
                while (__hip_atomic_load(ctr, __ATOMIC_RELAXED, __HIP_MEMORY_SCOPE_AGENT) < target
                       && ++spins < (1u<<22)) {}
            }
            __syncthreads();
            __threadfence();          // acquire: invalidate so next hs loads see fresh h
        }
    }

    if (tid < 128)
        cfin[(size_t)(bc*8 + ub)*HID + hid0 + uh] = creg;
}

extern "C" void kernel_launch(void* const* d_in, const int* in_sizes, int n_in,
                              void* d_out, int out_size, void* d_ws, size_t ws_size,
                              hipStream_t stream) {
    const int*   src      = (const int*)  d_in[0];
    const int*   trg      = (const int*)  d_in[1];
    const float* enc_emb  = (const float*)d_in[2];
    const float* enc_Wih0 = (const float*)d_in[3];
    const float* enc_Whh0 = (const float*)d_in[4];
    const float* enc_b0   = (const float*)d_in[5];
    const float* enc_Wih1 = (const float*)d_in[6];
    const float* enc_Whh1 = (const float*)d_in[7];
    const float* enc_b1   = (const float*)d_in[8];
    const float* dec_emb  = (const float*)d_in[9];
    const float* dec_Wih0 = (const float*)d_in[10];
    const float* dec_Whh0 = (const float*)d_in[11];
    const float* dec_b0   = (const float*)d_in[12];
    const float* dec_Wih1 = (const float*)d_in[13];
    const float* dec_Whh1 = (const float*)d_in[14];
    const float* dec_b1   = (const float*)d_in[15];
    const float* out_W    = (const float*)d_in[16];
    const float* out_b    = (const float*)d_in[17];

    // Big transient scratch in d_out (fp32, 100.35M elems); all dead before final GEMM.
    float* ob = (float*)d_out;
    float* Xp   = ob;                         // [3200,2048]
    float* xe   = ob + (size_t)6553600;       // [3200,256]
    float* xd   = ob + (size_t)7372800;       // [3136,256]
    float* eys0 = ob + (size_t)8175616;       // [50*64,512]
    float* eys1 = ob + (size_t)9814016;       // [50*64,512]
    float* dys0 = ob + (size_t)11452416;      // [49*64,512]

    // d_ws: survivors + states + barrier counters (~6.8 MB).
    float* ws = (float*)d_ws;
    float* dys1 = ws;                              // [49*64,512]
    float* c0   = ws + (size_t)1605632;            // [64,512]
    float* c1   = ws + (size_t)1638400;            // [64,512]
    float* hz   = ws + (size_t)1671168;            // [64,512] zeros
    unsigned* ctrs = (unsigned*)(ws + (size_t)1703936);  // 4 layers x 8 groups x 16 uints

    // zero c0,c1,hz + counters
    {
        int n = 3*BATCH*HID + 512;
        zero_kernel<<<(n+255)/256, 256, 0, stream>>>(c0, n);
    }

    // embeddings
    embed_kernel<<<(50*BATCH*(EMB/4)+255)/256, 256, 0, stream>>>(src, enc_emb, xe, 50);
    embed_kernel<<<(49*BATCH*(EMB/4)+255)/256, 256, 0, stream>>>(trg, dec_emb, xd, 49);

    dim3 xgrid(G4/128, 25);   // 16 x 25 for Xp GEMMs

    // ---- encoder layer 0 ----
    gemm_mfma_split<EMB, G4><<<xgrid, 256, 0, stream>>>(xe, enc_Wih0, enc_b0, Xp, 3200);
    lstm_layer_k<<<256, 256, 0, stream>>>(Xp, enc_Whh0, hz, hz, eys0, c0, 50, ctrs + 0);

    // ---- encoder layer 1 ----
    gemm_mfma_split<HID, G4><<<xgrid, 256, 0, stream>>>(eys0, enc_Wih1, enc_b1, Xp, 3200);
    lstm_layer_k<<<256, 256, 0, stream>>>(Xp, enc_Whh1, hz, hz, eys1, c1, 50, ctrs + 128);

    // ---- decoder layer 0 (h/c continue from encoder layer 0 finals) ----
    gemm_mfma_split<EMB, G4><<<xgrid, 256, 0, stream>>>(xd, dec_Wih0, dec_b0, Xp, 3136);
    lstm_layer_k<<<256, 256, 0, stream>>>(Xp, dec_Whh0, eys0 + (size_t)49*BATCH*HID, c0,
                                          dys0, c0, 49, ctrs + 256);

    // ---- decoder layer 1 (h/c continue from encoder layer 1 finals) ----
    gemm_mfma_split<HID, G4><<<xgrid, 256, 0, stream>>>(dys0, dec_Wih1, dec_b1, Xp, 3136);
    lstm_layer_k<<<256, 256, 0, stream>>>(Xp, dec_Whh1, eys1 + (size_t)49*BATCH*HID, c1,
                                          dys1, c1, 49, ctrs + 384);

    // ---- final projection -> fp32 d_out [3136, 32000] ----
    gemm_mfma_split<HID, VOCAB><<<dim3(VOCAB/128, 25), 256, 0, stream>>>(
        dys1, out_W, out_b, (float*)d_out, 3136);
}

// Round 6
// 4444.588 us; speedup vs baseline: 3.2239x; 2.3471x over previous
//
#include <hip/hip_runtime.h>
#include <hip/hip_bf16.h>

#define BATCH 64
#define HID 512
#define EMB 256
#define VOCAB 32000
#define G4 2048   // 4*HID

typedef __attribute__((ext_vector_type(8))) short short8;
typedef __attribute__((ext_vector_type(4))) float f32x4;

// ---------------- zero init ----------------
__global__ __launch_bounds__(256) void zero_kernel(float* p, int n){
    int i = blockIdx.x*256 + threadIdx.x;
    if (i < n) p[i] = 0.f;
}

// ---------------- embedding gather ----------------
__global__ __launch_bounds__(256) void embed_kernel(const int* __restrict__ tok,
                                                    const float* __restrict__ emb,
                                                    float* __restrict__ out, int T){
    int i = blockIdx.x*256 + threadIdx.x;
    int n = T*BATCH*(EMB/4);
    if (i >= n) return;
    int e4 = i % (EMB/4);
    int tb = i / (EMB/4);
    int id = tok[tb];
    reinterpret_cast<float4*>(out)[(size_t)tb*(EMB/4) + e4] =
        reinterpret_cast<const float4*>(emb + (size_t)id*EMB)[e4];
}

// round-to-nearest-even fp32 -> bf16 bits
__device__ __forceinline__ unsigned short bf16_rne(float x){
    unsigned b = __float_as_uint(x);
    return (unsigned short)((b + 0x7fffu + ((b >> 16) & 1u)) >> 16);
}

// ---------------- MFMA split-bf16 GEMM: C[n,m] = A[n,:K].B[m,:K] + bias[m] ----------------
// fp32 in/out; internally A,B split to bf16 hi/lo; C = AhBh + AhBl + AlBh (fp32 MFMA acc).
// Tile 128x128, 4 waves of 64x64, mfma 16x16x32. KDIM mult of 32; NDIM mult of 128.
template<int KDIM, int NDIM>
__global__ __launch_bounds__(256) void gemm_mfma_split(
    const float* __restrict__ A, const float* __restrict__ B,
    const float* __restrict__ bias, float* __restrict__ C, int M)
{
    constexpr int LS = 40;   // LDS row stride in bf16 elems (32 data + 8 pad)
    __shared__ unsigned short Ah[128*LS], Al[128*LS], Bh[128*LS], Bl[128*LS];
    const int n0 = blockIdx.x*128, m0 = blockIdx.y*128;
    const int tid  = threadIdx.x;
    const int lane = tid & 63, wid = tid >> 6;
    const int wm = wid >> 1, wn = wid & 1;
    const int srow = tid >> 1, sk = (tid & 1)*16;
    f32x4 acc[4][4] = {};

    for (int k0 = 0; k0 < KDIM; k0 += 32){
        __syncthreads();
        {
            int ar = m0 + srow;
            float xv[16];
            if (ar < M){
                const float4* ap = reinterpret_cast<const float4*>(A + (size_t)ar*KDIM + k0 + sk);
                #pragma unroll
                for (int q = 0; q < 4; q++){
                    float4 v = ap[q];
                    xv[q*4+0]=v.x; xv[q*4+1]=v.y; xv[q*4+2]=v.z; xv[q*4+3]=v.w;
                }
            } else {
                #pragma unroll
                for (int q = 0; q < 16; q++) xv[q] = 0.f;
            }
            #pragma unroll
            for (int q = 0; q < 16; q++){
                unsigned short h = bf16_rne(xv[q]);
                float hf = __uint_as_float((unsigned)h << 16);
                Ah[srow*LS + sk + q] = h;
                Al[srow*LS + sk + q] = bf16_rne(xv[q] - hf);
            }
        }
        {
            int br = n0 + srow;
            const float4* bp = reinterpret_cast<const float4*>(B + (size_t)br*KDIM + k0 + sk);
            #pragma unroll
            for (int q = 0; q < 4; q++){
                float4 v = bp[q];
                float xs[4] = {v.x, v.y, v.z, v.w};
                #pragma unroll
                for (int j = 0; j < 4; j++){
                    unsigned short h = bf16_rne(xs[j]);
                    float hf = __uint_as_float((unsigned)h << 16);
                    Bh[srow*LS + sk + q*4 + j] = h;
                    Bl[srow*LS + sk + q*4 + j] = bf16_rne(xs[j] - hf);
                }
            }
        }
        __syncthreads();
        const int fr = lane & 15, fk = (lane >> 4)*8;
        short8 a_h[4], a_l[4], b_h[4], b_l[4];
        #pragma unroll
        for (int mi = 0; mi < 4; mi++){
            int row = wm*64 + mi*16 + fr;
            a_h[mi] = *reinterpret_cast<const short8*>(&Ah[row*LS + fk]);
            a_l[mi] = *reinterpret_cast<const short8*>(&Al[row*LS + fk]);
        }
        #pragma unroll
        for (int nj = 0; nj < 4; nj++){
            int rowb = wn*64 + nj*16 + fr;
            b_h[nj] = *reinterpret_cast<const short8*>(&Bh[rowb*LS + fk]);
            b_l[nj] = *reinterpret_cast<const short8*>(&Bl[rowb*LS + fk]);
        }
        #pragma unroll
        for (int mi = 0; mi < 4; mi++)
            #pragma unroll
            for (int nj = 0; nj < 4; nj++){
                acc[mi][nj] = __builtin_amdgcn_mfma_f32_16x16x32_bf16(a_h[mi], b_h[nj], acc[mi][nj], 0,0,0);
                acc[mi][nj] = __builtin_amdgcn_mfma_f32_16x16x32_bf16(a_h[mi], b_l[nj], acc[mi][nj], 0,0,0);
                acc[mi][nj] = __builtin_amdgcn_mfma_f32_16x16x32_bf16(a_l[mi], b_h[nj], acc[mi][nj], 0,0,0);
            }
    }
    const int fr = lane & 15, fq = lane >> 4;
    #pragma unroll
    for (int nj = 0; nj < 4; nj++){
        int col = n0 + wn*64 + nj*16 + fr;
        float bv = bias[col];
        #pragma unroll
        for (int mi = 0; mi < 4; mi++){
            int rbase = m0 + wm*64 + mi*16 + fq*4;
            #pragma unroll
            for (int j = 0; j < 4; j++){
                int row = rbase + j;
                if (row < M)
                    __builtin_nontemporal_store(acc[mi][nj][j] + bv, &C[(size_t)row*NDIM + col]);
            }
        }
    }
}

// ---------------- persistent LSTM layer ----------------
// 256 blocks x 256 threads. Block (hc=bx&31, bc=bx>>5): 16 hid x 8 batch outputs.
// Whh slice register-resident. Step-crossing data (h, counters) moves through the
// DEVICE COHERENCE POINT via relaxed agent-scope atomics (uncached, bypass L1/L2)
// -> zero __threadfence (no buffer_wbl2 / buffer_inv L2-maintenance storms, the
// round-4/5 bottleneck). Ordering: explicit s_waitcnt vmcnt(0) + __syncthreads
// before the arrive-add guarantees all waves' h stores are complete at the
// coherence point before the count increments; consumers load h only after
// observing the count (data-dependent), so values are fresh. Spin is bounded:
// a sync bug terminates wrong rather than hanging.
__global__ __launch_bounds__(256, 1) void lstm_layer_k(
    const float* __restrict__ Xp,    // [T*64, 2048]
    const float* __restrict__ Whh,   // [2048, 512]
    const float* __restrict__ hinit, // [64, 512]
    const float* __restrict__ cinit, // [64, 512]
    float* __restrict__ ys,          // [T*64, 512]
    float* __restrict__ cfin,        // [64, 512]
    int T,
    unsigned* __restrict__ ctrbase)  // 8 groups x 16 uints, zeroed per launch
{
    __shared__ float hs[8*HID];      // 16 KB
    __shared__ float red[4*64*8];    // 8 KB

    const int bx  = blockIdx.x;
    const int hc  = bx & 31, bc = bx >> 5;
    const int hid0 = hc*16;
    const int tid = threadIdx.x;
    const int r   = tid & 63, kc = tid >> 6;
    const int g   = r >> 4, hl = r & 15;
    const int gr  = g*HID + hid0 + hl;
    unsigned* ctr = ctrbase + bc*16;

    float4 w[32];
    {
        const float4* wp = reinterpret_cast<const float4*>(Whh + (size_t)gr*HID) + kc*32;
        #pragma unroll
        for (int j = 0; j < 32; j++) w[j] = wp[j];
    }

    const int ub = tid >> 4;
    const int uh = tid & 15;
    float creg = 0.f;
    if (tid < 128) creg = cinit[(size_t)(bc*8 + ub)*HID + hid0 + uh];

    const size_t hbase = (size_t)bc*8*HID;

    for (int t = 0; t < T; t++){
        // ---- stage h(t-1) into LDS via coherent (uncached) loads ----
        {
            const float* hsrc = (t == 0) ? (hinit + hbase)
                                         : (ys + (size_t)(t-1)*BATCH*HID + hbase);
            #pragma unroll
            for (int j = 0; j < 16; j++)
                hs[tid + j*256] = __hip_atomic_load(&hsrc[tid + j*256],
                                                    __ATOMIC_RELAXED, __HIP_MEMORY_SCOPE_AGENT);
        }
        __syncthreads();

        // ---- partial dots ----
        float4 a4[8];
        #pragma unroll
        for (int b = 0; b < 8; b++) a4[b] = float4{0.f,0.f,0.f,0.f};
        const float4* h4 = reinterpret_cast<const float4*>(hs) + kc*32;
        #pragma unroll
        for (int j = 0; j < 32; j++){
            float4 a = w[j];
            #pragma unroll
            for (int b = 0; b < 8; b++){
                float4 hv = h4[b*128 + j];
                a4[b].x += a.x*hv.x; a4[b].y += a.y*hv.y;
                a4[b].z += a.z*hv.z; a4[b].w += a.w*hv.w;
            }
        }
        #pragma unroll
        for (int b = 0; b < 8; b++)
            red[(kc*64 + r)*8 + b] = a4[b].x + a4[b].y + a4[b].z + a4[b].w;
        __syncthreads();

        if (tid < 64){
            #pragma unroll
            for (int b = 0; b < 8; b++)
                red[tid*8 + b] = red[tid*8 + b] + red[(64+tid)*8 + b]
                               + red[(128+tid)*8 + b] + red[(192+tid)*8 + b];
        }
        __syncthreads();

        if (tid < 128){
            float gd0 = red[(0*16 + uh)*8 + ub];
            float gd1 = red[(1*16 + uh)*8 + ub];
            float gd2 = red[(2*16 + uh)*8 + ub];
            float gd3 = red[(3*16 + uh)*8 + ub];
            const float* xpr = Xp + (size_t)t*BATCH*G4 + (size_t)(bc*8 + ub)*G4 + hid0 + uh;
            float gi = gd0 + xpr[0];
            float gf = gd1 + xpr[512];
            float gg = gd2 + xpr[1024];
            float go = gd3 + xpr[1536];
            float si = 1.f/(1.f + expf(-gi));
            float sf = 1.f/(1.f + expf(-gf));
            float so = 1.f/(1.f + expf(-go));
            float tg = tanhf(gg);
            float c = sf*creg + si*tg;
            creg = c;
            // h(t) -> coherence point (uncached store; no fence needed)
            __hip_atomic_store(&ys[(size_t)t*BATCH*HID + (size_t)(bc*8 + ub)*HID + hid0 + uh],
                               so * tanhf(c), __ATOMIC_RELAXED, __HIP_MEMORY_SCOPE_AGENT);
        }

        // ---- per-bc-group barrier (32 blocks), fence-free ----
        if (t < T-1){
            // each wave drains its own h stores, then block-converges:
            asm volatile("s_waitcnt vmcnt(0)" ::: "memory");
            __syncthreads();
            if (tid == 0){
                __hip_atomic_fetch_add(ctr, 1u, __ATOMIC_RELAXED, __HIP_MEMORY_SCOPE_AGENT);
                unsigned target = (unsigned)(t+1) * 32u;
                unsigned spins = 0;
                while (__hip_atomic_load(ctr, __ATOMIC_RELAXED, __HIP_MEMORY_SCOPE_AGENT) < target
                       && ++spins < (1u<<19)) {
                    __builtin_amdgcn_s_sleep(1);
                }
            }
            __syncthreads();
        }
    }

    if (tid < 128)
        cfin[(size_t)(bc*8 + ub)*HID + hid0 + uh] = creg;
}

extern "C" void kernel_launch(void* const* d_in, const int* in_sizes, int n_in,
                              void* d_out, int out_size, void* d_ws, size_t ws_size,
                              hipStream_t stream) {
    const int*   src      = (const int*)  d_in[0];
    const int*   trg      = (const int*)  d_in[1];
    const float* enc_emb  = (const float*)d_in[2];
    const float* enc_Wih0 = (const float*)d_in[3];
    const float* enc_Whh0 = (const float*)d_in[4];
    const float* enc_b0   = (const float*)d_in[5];
    const float* enc_Wih1 = (const float*)d_in[6];
    const float* enc_Whh1 = (const float*)d_in[7];
    const float* enc_b1   = (const float*)d_in[8];
    const float* dec_emb  = (const float*)d_in[9];
    const float* dec_Wih0 = (const float*)d_in[10];
    const float* dec_Whh0 = (const float*)d_in[11];
    const float* dec_b0   = (const float*)d_in[12];
    const float* dec_Wih1 = (const float*)d_in[13];
    const float* dec_Whh1 = (const float*)d_in[14];
    const float* dec_b1   = (const float*)d_in[15];
    const float* out_W    = (const float*)d_in[16];
    const float* out_b    = (const float*)d_in[17];

    // Big transient scratch in d_out (fp32, 100.35M elems); all dead before final GEMM.
    float* ob = (float*)d_out;
    float* Xp   = ob;                         // [3200,2048]
    float* xe   = ob + (size_t)6553600;       // [3200,256]
    float* xd   = ob + (size_t)7372800;       // [3136,256]
    float* eys0 = ob + (size_t)8175616;       // [50*64,512]
    float* eys1 = ob + (size_t)9814016;       // [50*64,512]
    float* dys0 = ob + (size_t)11452416;      // [49*64,512]

    // d_ws: survivors + states + barrier counters (~6.8 MB).
    float* ws = (float*)d_ws;
    float* dys1 = ws;                              // [49*64,512]
    float* c0   = ws + (size_t)1605632;            // [64,512]
    float* c1   = ws + (size_t)1638400;            // [64,512]
    float* hz   = ws + (size_t)1671168;            // [64,512] zeros
    unsigned* ctrs = (unsigned*)(ws + (size_t)1703936);  // 4 layers x 8 groups x 16 uints

    // zero c0,c1,hz + counters (re-zeroed every launch -> graph-replay safe)
    {
        int n = 3*BATCH*HID + 512;
        zero_kernel<<<(n+255)/256, 256, 0, stream>>>(c0, n);
    }

    // embeddings
    embed_kernel<<<(50*BATCH*(EMB/4)+255)/256, 256, 0, stream>>>(src, enc_emb, xe, 50);
    embed_kernel<<<(49*BATCH*(EMB/4)+255)/256, 256, 0, stream>>>(trg, dec_emb, xd, 49);

    dim3 xgrid(G4/128, 25);

    // ---- encoder layer 0 ----
    gemm_mfma_split<EMB, G4><<<xgrid, 256, 0, stream>>>(xe, enc_Wih0, enc_b0, Xp, 3200);
    lstm_layer_k<<<256, 256, 0, stream>>>(Xp, enc_Whh0, hz, hz, eys0, c0, 50, ctrs + 0);

    // ---- encoder layer 1 ----
    gemm_mfma_split<HID, G4><<<xgrid, 256, 0, stream>>>(eys0, enc_Wih1, enc_b1, Xp, 3200);
    lstm_layer_k<<<256, 256, 0, stream>>>(Xp, enc_Whh1, hz, hz, eys1, c1, 50, ctrs + 128);

    // ---- decoder layer 0 (h/c continue from encoder layer 0 finals) ----
    gemm_mfma_split<EMB, G4><<<xgrid, 256, 0, stream>>>(xd, dec_Wih0, dec_b0, Xp, 3136);
    lstm_layer_k<<<256, 256, 0, stream>>>(Xp, dec_Whh0, eys0 + (size_t)49*BATCH*HID, c0,
                                          dys0, c0, 49, ctrs + 256);

    // ---- decoder layer 1 (h/c continue from encoder layer 1 finals) ----
    gemm_mfma_split<HID, G4><<<xgrid, 256, 0, stream>>>(dys0, dec_Wih1, dec_b1, Xp, 3136);
    lstm_layer_k<<<256, 256, 0, stream>>>(Xp, dec_Whh1, eys1 + (size_t)49*BATCH*HID, c1,
                                          dys1, c1, 49, ctrs + 384);

    // ---- final projection -> fp32 d_out [3136, 32000] ----
    gemm_mfma_split<HID, VOCAB><<<dim3(VOCAB/128, 25), 256, 0, stream>>>(
        dys1, out_W, out_b, (float*)d_out, 3136);
}

// Round 7
// 3199.959 us; speedup vs baseline: 4.4778x; 1.3890x over previous
//
#include <hip/hip_runtime.h>
#include <hip/hip_bf16.h>

#define BATCH 64
#define HID 512
#define EMB 256
#define VOCAB 32000
#define G4 2048   // 4*HID

typedef __attribute__((ext_vector_type(8))) short short8;
typedef __attribute__((ext_vector_type(4))) float f32x4;

// ---------------- zero init ----------------
__global__ __launch_bounds__(256) void zero_kernel(float* p, int n){
    int i = blockIdx.x*256 + threadIdx.x;
    if (i < n) p[i] = 0.f;
}

// ---------------- embedding gather ----------------
__global__ __launch_bounds__(256) void embed_kernel(const int* __restrict__ tok,
                                                    const float* __restrict__ emb,
                                                    float* __restrict__ out, int T){
    int i = blockIdx.x*256 + threadIdx.x;
    int n = T*BATCH*(EMB/4);
    if (i >= n) return;
    int e4 = i % (EMB/4);
    int tb = i / (EMB/4);
    int id = tok[tb];
    reinterpret_cast<float4*>(out)[(size_t)tb*(EMB/4) + e4] =
        reinterpret_cast<const float4*>(emb + (size_t)id*EMB)[e4];
}

// round-to-nearest-even fp32 -> bf16 bits
__device__ __forceinline__ unsigned short bf16_rne(float x){
    unsigned b = __float_as_uint(x);
    return (unsigned short)((b + 0x7fffu + ((b >> 16) & 1u)) >> 16);
}

// ---------------- MFMA split-bf16 GEMM (unchanged from round 5) ----------------
template<int KDIM, int NDIM>
__global__ __launch_bounds__(256) void gemm_mfma_split(
    const float* __restrict__ A, const float* __restrict__ B,
    const float* __restrict__ bias, float* __restrict__ C, int M)
{
    constexpr int LS = 40;
    __shared__ unsigned short Ah[128*LS], Al[128*LS], Bh[128*LS], Bl[128*LS];
    const int n0 = blockIdx.x*128, m0 = blockIdx.y*128;
    const int tid  = threadIdx.x;
    const int lane = tid & 63, wid = tid >> 6;
    const int wm = wid >> 1, wn = wid & 1;
    const int srow = tid >> 1, sk = (tid & 1)*16;
    f32x4 acc[4][4] = {};

    for (int k0 = 0; k0 < KDIM; k0 += 32){
        __syncthreads();
        {
            int ar = m0 + srow;
            float xv[16];
            if (ar < M){
                const float4* ap = reinterpret_cast<const float4*>(A + (size_t)ar*KDIM + k0 + sk);
                #pragma unroll
                for (int q = 0; q < 4; q++){
                    float4 v = ap[q];
                    xv[q*4+0]=v.x; xv[q*4+1]=v.y; xv[q*4+2]=v.z; xv[q*4+3]=v.w;
                }
            } else {
                #pragma unroll
                for (int q = 0; q < 16; q++) xv[q] = 0.f;
            }
            #pragma unroll
            for (int q = 0; q < 16; q++){
                unsigned short h = bf16_rne(xv[q]);
                float hf = __uint_as_float((unsigned)h << 16);
                Ah[srow*LS + sk + q] = h;
                Al[srow*LS + sk + q] = bf16_rne(xv[q] - hf);
            }
        }
        {
            int br = n0 + srow;
            const float4* bp = reinterpret_cast<const float4*>(B + (size_t)br*KDIM + k0 + sk);
            #pragma unroll
            for (int q = 0; q < 4; q++){
                float4 v = bp[q];
                float xs[4] = {v.x, v.y, v.z, v.w};
                #pragma unroll
                for (int j = 0; j < 4; j++){
                    unsigned short h = bf16_rne(xs[j]);
                    float hf = __uint_as_float((unsigned)h << 16);
                    Bh[srow*LS + sk + q*4 + j] = h;
                    Bl[srow*LS + sk + q*4 + j] = bf16_rne(xs[j] - hf);
                }
            }
        }
        __syncthreads();
        const int fr = lane & 15, fk = (lane >> 4)*8;
        short8 a_h[4], a_l[4], b_h[4], b_l[4];
        #pragma unroll
        for (int mi = 0; mi < 4; mi++){
            int row = wm*64 + mi*16 + fr;
            a_h[mi] = *reinterpret_cast<const short8*>(&Ah[row*LS + fk]);
            a_l[mi] = *reinterpret_cast<const short8*>(&Al[row*LS + fk]);
        }
        #pragma unroll
        for (int nj = 0; nj < 4; nj++){
            int rowb = wn*64 + nj*16 + fr;
            b_h[nj] = *reinterpret_cast<const short8*>(&Bh[rowb*LS + fk]);
            b_l[nj] = *reinterpret_cast<const short8*>(&Bl[rowb*LS + fk]);
        }
        #pragma unroll
        for (int mi = 0; mi < 4; mi++)
            #pragma unroll
            for (int nj = 0; nj < 4; nj++){
                acc[mi][nj] = __builtin_amdgcn_mfma_f32_16x16x32_bf16(a_h[mi], b_h[nj], acc[mi][nj], 0,0,0);
                acc[mi][nj] = __builtin_amdgcn_mfma_f32_16x16x32_bf16(a_h[mi], b_l[nj], acc[mi][nj], 0,0,0);
                acc[mi][nj] = __builtin_amdgcn_mfma_f32_16x16x32_bf16(a_l[mi], b_h[nj], acc[mi][nj], 0,0,0);
            }
    }
    const int fr = lane & 15, fq = lane >> 4;
    #pragma unroll
    for (int nj = 0; nj < 4; nj++){
        int col = n0 + wn*64 + nj*16 + fr;
        float bv = bias[col];
        #pragma unroll
        for (int mi = 0; mi < 4; mi++){
            int rbase = m0 + wm*64 + mi*16 + fq*4;
            #pragma unroll
            for (int j = 0; j < 4; j++){
                int row = rbase + j;
                if (row < M)
                    __builtin_nontemporal_store(acc[mi][nj][j] + bv, &C[(size_t)row*NDIM + col]);
            }
        }
    }
}

// ---- batched uncached (coherence-point) 16B loads: 4 x dwordx4 + one vmcnt ----
__device__ __forceinline__ void stage_h16(const f32x4* base, f32x4* dst, int tid){
    f32x4 a, b, c, d;
    const f32x4* p0 = base + tid;
    const f32x4* p1 = base + tid + 256;
    const f32x4* p2 = base + tid + 512;
    const f32x4* p3 = base + tid + 768;
    asm volatile(
        "global_load_dwordx4 %0, %4, off sc0 sc1\n\t"
        "global_load_dwordx4 %1, %5, off sc0 sc1\n\t"
        "global_load_dwordx4 %2, %6, off sc0 sc1\n\t"
        "global_load_dwordx4 %3, %7, off sc0 sc1\n\t"
        "s_waitcnt vmcnt(0)"
        : "=&v"(a), "=&v"(b), "=&v"(c), "=&v"(d)
        : "v"(p0), "v"(p1), "v"(p2), "v"(p3)
        : "memory");
    dst[tid]       = a;
    dst[tid + 256] = b;
    dst[tid + 512] = c;
    dst[tid + 768] = d;
}

// ---------------- persistent LSTM layer ----------------
// 256 blocks x 256 threads. Block (hc=bx&31, bc=bx>>5): 16 hid x 8 batch outputs.
// Whh slice register-resident. Step-crossing data moves through the device
// coherence point via sc0/sc1 accesses (no fences anywhere).
// Barrier (per bc-group of 32 blocks), CONTENTION-FREE:
//   arrive: tid0 stores epoch t+1 to its OWN 64B-spaced flag (plain store, no RMW)
//   wait:   lanes 0..31 of wave 0 poll the 32 flags in parallel until __all >= t+1
// Ordering: each thread drains its h stores (vmcnt 0) before __syncthreads; tid0's
// flag store issues after -> flag visible implies h visible at coherence point.
// Xp for step t+1 is prefetched into registers between arrive and poll.
// Spin bounded: a sync bug terminates wrong rather than hanging.
__global__ __launch_bounds__(256, 1) void lstm_layer_k(
    const float* __restrict__ Xp,    // [T*64, 2048]
    const float* __restrict__ Whh,   // [2048, 512]
    const float* __restrict__ hinit, // [64, 512]
    const float* __restrict__ cinit, // [64, 512]
    float* __restrict__ ys,          // [T*64, 512]
    float* __restrict__ cfin,        // [64, 512]
    int T,
    unsigned* __restrict__ flagbase) // 8 groups x 32 members x 16 uints, zeroed
{
    __shared__ f32x4 hs4[1024];      // 16 KB (16B aligned)
    __shared__ float red[4*64*8];    // 8 KB
    float* hs = (float*)hs4;

    const int bx  = blockIdx.x;
    const int hc  = bx & 31, bc = bx >> 5;
    const int hid0 = hc*16;
    const int tid = threadIdx.x;
    const int r   = tid & 63, kc = tid >> 6;
    const int g   = r >> 4, hl = r & 15;
    const int gr  = g*HID + hid0 + hl;
    unsigned* myflag = flagbase + (size_t)(bc*32 + hc)*16;

    float4 w[32];
    {
        const float4* wp = reinterpret_cast<const float4*>(Whh + (size_t)gr*HID) + kc*32;
        #pragma unroll
        for (int j = 0; j < 32; j++) w[j] = wp[j];
    }

    const int ub = tid >> 4;   // batch (tid<128)
    const int uh = tid & 15;   // hid
    float creg = 0.f;
    if (tid < 128) creg = cinit[(size_t)(bc*8 + ub)*HID + hid0 + uh];

    const size_t hbase = (size_t)bc*8*HID;
    const float* xprow = Xp + (size_t)(bc*8 + ub)*G4 + hid0 + uh;  // valid for tid<128

    // prefetch Xp for t=0
    float xn0=0.f, xn1=0.f, xn2=0.f, xn3=0.f;
    if (tid < 128){
        const float* xpr = xprow;
        xn0 = xpr[0]; xn1 = xpr[512]; xn2 = xpr[1024]; xn3 = xpr[1536];
    }

    for (int t = 0; t < T; t++){
        // ---- stage h(t-1) into LDS (wide uncached loads, single vmcnt) ----
        {
            const float* hsrc = (t == 0) ? (hinit + hbase)
                                         : (ys + (size_t)(t-1)*BATCH*HID + hbase);
            stage_h16(reinterpret_cast<const f32x4*>(hsrc), hs4, tid);
        }
        __syncthreads();

        // ---- partial dots ----
        float4 a4[8];
        #pragma unroll
        for (int b = 0; b < 8; b++) a4[b] = float4{0.f,0.f,0.f,0.f};
        const float4* h4 = reinterpret_cast<const float4*>(hs) + kc*32;
        #pragma unroll
        for (int j = 0; j < 32; j++){
            float4 a = w[j];
            #pragma unroll
            for (int b = 0; b < 8; b++){
                float4 hv = h4[b*128 + j];
                a4[b].x += a.x*hv.x; a4[b].y += a.y*hv.y;
                a4[b].z += a.z*hv.z; a4[b].w += a.w*hv.w;
            }
        }
        #pragma unroll
        for (int b = 0; b < 8; b++)
            red[(kc*64 + r)*8 + b] = a4[b].x + a4[b].y + a4[b].z + a4[b].w;
        __syncthreads();

        if (tid < 64){
            #pragma unroll
            for (int b = 0; b < 8; b++)
                red[tid*8 + b] = red[tid*8 + b] + red[(64+tid)*8 + b]
                               + red[(128+tid)*8 + b] + red[(192+tid)*8 + b];
        }
        __syncthreads();

        // ---- gates + state update ----
        if (tid < 128){
            float gi = red[(0*16 + uh)*8 + ub] + xn0;
            float gf = red[(1*16 + uh)*8 + ub] + xn1;
            float gg = red[(2*16 + uh)*8 + ub] + xn2;
            float go = red[(3*16 + uh)*8 + ub] + xn3;
            float si = 1.f/(1.f + expf(-gi));
            float sf = 1.f/(1.f + expf(-gf));
            float so = 1.f/(1.f + expf(-go));
            float tg = tanhf(gg);
            float c = sf*creg + si*tg;
            creg = c;
            __hip_atomic_store(&ys[(size_t)t*BATCH*HID + (size_t)(bc*8 + ub)*HID + hid0 + uh],
                               so * tanhf(c), __ATOMIC_RELAXED, __HIP_MEMORY_SCOPE_AGENT);
        }

        // ---- contention-free group barrier ----
        if (t < T-1){
            asm volatile("s_waitcnt vmcnt(0)" ::: "memory");  // drain own h stores
            __syncthreads();                                   // all waves drained
            if (tid == 0)
                __hip_atomic_store(myflag, (unsigned)(t+1),
                                   __ATOMIC_RELAXED, __HIP_MEMORY_SCOPE_AGENT);
            // prefetch next step's Xp while others arrive (cached loads)
            if (tid < 128){
                const float* xpr = xprow + (size_t)(t+1)*BATCH*G4;
                xn0 = xpr[0]; xn1 = xpr[512]; xn2 = xpr[1024]; xn3 = xpr[1536];
            }
            if (tid < 64){
                const unsigned tgt = (unsigned)(t+1);
                unsigned* fp = flagbase + (size_t)(bc*32 + (tid & 31))*16;
                unsigned spins = 0;
                bool done = false;
                while (!done && spins < (1u<<20)){
                    unsigned v = tgt;
                    if (tid < 32)
                        v = __hip_atomic_load(fp, __ATOMIC_RELAXED, __HIP_MEMORY_SCOPE_AGENT);
                    done = (bool)__all((int)(v >= tgt));
                    spins++;
                }
            }
            __syncthreads();
        }
    }

    if (tid < 128)
        cfin[(size_t)(bc*8 + ub)*HID + hid0 + uh] = creg;
}

extern "C" void kernel_launch(void* const* d_in, const int* in_sizes, int n_in,
                              void* d_out, int out_size, void* d_ws, size_t ws_size,
                              hipStream_t stream) {
    const int*   src      = (const int*)  d_in[0];
    const int*   trg      = (const int*)  d_in[1];
    const float* enc_emb  = (const float*)d_in[2];
    const float* enc_Wih0 = (const float*)d_in[3];
    const float* enc_Whh0 = (const float*)d_in[4];
    const float* enc_b0   = (const float*)d_in[5];
    const float* enc_Wih1 = (const float*)d_in[6];
    const float* enc_Whh1 = (const float*)d_in[7];
    const float* enc_b1   = (const float*)d_in[8];
    const float* dec_emb  = (const float*)d_in[9];
    const float* dec_Wih0 = (const float*)d_in[10];
    const float* dec_Whh0 = (const float*)d_in[11];
    const float* dec_b0   = (const float*)d_in[12];
    const float* dec_Wih1 = (const float*)d_in[13];
    const float* dec_Whh1 = (const float*)d_in[14];
    const float* dec_b1   = (const float*)d_in[15];
    const float* out_W    = (const float*)d_in[16];
    const float* out_b    = (const float*)d_in[17];

    // Big transient scratch in d_out (fp32, 100.35M elems); all dead before final GEMM.
    float* ob = (float*)d_out;
    float* Xp   = ob;                         // [3200,2048]
    float* xe   = ob + (size_t)6553600;       // [3200,256]
    float* xd   = ob + (size_t)7372800;       // [3136,256]
    float* eys0 = ob + (size_t)8175616;       // [50*64,512]
    float* eys1 = ob + (size_t)9814016;       // [50*64,512]
    float* dys0 = ob + (size_t)11452416;      // [49*64,512]

    // d_ws: survivors + states + barrier flags (~7 MB).
    float* ws = (float*)d_ws;
    float* dys1 = ws;                              // [49*64,512]
    float* c0   = ws + (size_t)1605632;            // [64,512]
    float* c1   = ws + (size_t)1638400;            // [64,512]
    float* hz   = ws + (size_t)1671168;            // [64,512] zeros
    unsigned* flags = (unsigned*)(ws + (size_t)1703936); // 4 layers x 8 grp x 32 x 16 uints

    // zero c0,c1,hz + flags (re-zeroed every launch -> graph-replay safe)
    {
        int n = 3*BATCH*HID + 4*4096;
        zero_kernel<<<(n+255)/256, 256, 0, stream>>>(c0, n);
    }

    // embeddings
    embed_kernel<<<(50*BATCH*(EMB/4)+255)/256, 256, 0, stream>>>(src, enc_emb, xe, 50);
    embed_kernel<<<(49*BATCH*(EMB/4)+255)/256, 256, 0, stream>>>(trg, dec_emb, xd, 49);

    dim3 xgrid(G4/128, 25);

    // ---- encoder layer 0 ----
    gemm_mfma_split<EMB, G4><<<xgrid, 256, 0, stream>>>(xe, enc_Wih0, enc_b0, Xp, 3200);
    lstm_layer_k<<<256, 256, 0, stream>>>(Xp, enc_Whh0, hz, hz, eys0, c0, 50, flags + 0);

    // ---- encoder layer 1 ----
    gemm_mfma_split<HID, G4><<<xgrid, 256, 0, stream>>>(eys0, enc_Wih1, enc_b1, Xp, 3200);
    lstm_layer_k<<<256, 256, 0, stream>>>(Xp, enc_Whh1, hz, hz, eys1, c1, 50, flags + 4096);

    // ---- decoder layer 0 (h/c continue from encoder layer 0 finals) ----
    gemm_mfma_split<EMB, G4><<<xgrid, 256, 0, stream>>>(xd, dec_Wih0, dec_b0, Xp, 3136);
    lstm_layer_k<<<256, 256, 0, stream>>>(Xp, dec_Whh0, eys0 + (size_t)49*BATCH*HID, c0,
                                          dys0, c0, 49, flags + 8192);

    // ---- decoder layer 1 (h/c continue from encoder layer 1 finals) ----
    gemm_mfma_split<HID, G4><<<xgrid, 256, 0, stream>>>(dys0, dec_Wih1, dec_b1, Xp, 3136);
    lstm_layer_k<<<256, 256, 0, stream>>>(Xp, dec_Whh1, eys1 + (size_t)49*BATCH*HID, c1,
                                          dys1, c1, 49, flags + 12288);

    // ---- final projection -> fp32 d_out [3136, 32000] ----
    gemm_mfma_split<HID, VOCAB><<<dim3(VOCAB/128, 25), 256, 0, stream>>>(
        dys1, out_W, out_b, (float*)d_out, 3136);
}